// Round 3
// baseline (262.048 us; speedup 1.0000x reference)
//
#include <hip/hip_runtime.h>
#include <hip/hip_bf16.h>

#define Bc  4
#define NFc 5
#define HSc 512
#define Sc  1024

// x[b, ff, jj, ii]  (float32 input)
#define X(ff,jj,ii) x[xb + ((size_t)(ff)*HSc + (size_t)(jj))*Sc + (size_t)(ii)]
// weight arrays: arr[k, m] with leading-dim stride (float32)
#define LW(arr,k,stride,m) (arr)[(k)*(stride)+(m)]

__global__ __launch_bounds__(256) void icograd_kernel(
    const float* __restrict__ x,    const float* __restrict__ poles,
    const float* __restrict__ wi,   const float* __restrict__ we,
    const float* __restrict__ wcn,  const float* __restrict__ wne,
    const float* __restrict__ wnne, const float* __restrict__ wnw,
    const float* __restrict__ wnww, const float* __restrict__ wwe,
    const float* __restrict__ wsw,  const float* __restrict__ wsse,
    const float* __restrict__ wse,  const float* __restrict__ wcs,
    float* __restrict__ out)
{
    const int i  = blockIdx.x * blockDim.x + threadIdx.x;
    const int j  = blockIdx.y;
    const int bf = blockIdx.z;
    const int b  = bf / NFc;
    const int f  = bf % NFc;

    const size_t xb = (size_t)b * (NFc * HSc * Sc);
    const float  cc = X(f, j, i);
    const int fp = (f == 0) ? 4 : f - 1;   // _wrap_prev feature
    const int fn = (f == 4) ? 0 : f + 1;   // _wrap_next feature

    float c0, c1, c2, c3;

    if (j > 0 && j < HSc - 1) {
        if (i > 0 && i < Sc - 1) {
            // ---- inner ----
            const int wb = (j - 1) * (Sc - 2) + (i - 1);
            const int ws = (HSc - 2) * (Sc - 2);
            const float w0 = wi[wb];
            const float w1 = wi[wb + ws];
            const float w2 = wi[wb + 2 * ws];
            const float w3 = wi[wb + 3 * ws];
            const float w4 = wi[wb + 4 * ws];
            const float w5 = wi[wb + 5 * ws];
            c0 = (X(f, j - 1, i - 1) - cc) * w0;
            c1 = (X(f, j + 1, i + 1) - cc) * w1;
            c2 = (X(f, j - 1, i)     - cc) * w2 + (X(f, j,     i + 1) - cc) * w3;
            c3 = (X(f, j,     i - 1) - cc) * w4 + (X(f, j + 1, i)     - cc) * w5;
        } else if (i == 0) {
            // ---- SE: rows 1..HS-2, col 0 ----
            const int m = j - 1;
            c0 = (X(fp, HSc - 1, 511 - m) - cc) * LW(wse, 0, 510, m)
               + (X(fp, HSc - 1, 510 - m) - cc) * LW(wse, 1, 510, m);
            c1 = (X(f, j,     1) - cc) * LW(wse, 2, 510, m)
               + (X(f, j + 1, 1) - cc) * LW(wse, 3, 510, m);
            c2 = (X(f, j - 1, 0) - cc) * LW(wse, 4, 510, m);
            c3 = (X(f, j + 1, 0) - cc) * LW(wse, 5, 510, m);
        } else {
            // ---- NW: rows 1..HS-2, col S-1 ----
            const int m = j - 1;
            c0 = (X(f, j - 1, Sc - 2) - cc) * LW(wnw, 0, 510, m);
            c1 = (X(fn, 0, Sc - 2 - m) - cc) * LW(wnw, 1, 510, m);
            c2 = (X(f, j - 1, Sc - 1) - cc) * LW(wnw, 2, 510, m)
               + (X(fn, 0, Sc - 1 - m) - cc) * LW(wnw, 3, 510, m);
            c3 = (X(f, j,     Sc - 2) - cc) * LW(wnw, 4, 510, m)
               + (X(f, j + 1, Sc - 1) - cc) * LW(wnw, 5, 510, m);
        }
    } else if (j == 0) {
        if (i == 0) {
            // ---- CS ----
            c0 = (X(fp, HSc - 1, HSc - 1) - cc) * LW(wcs, 0, 1, 0);
            c1 = (X(f, 1, 1) - cc) * LW(wcs, 1, 1, 0);
            c2 = (X(fp, HSc - 1, HSc) - cc) * LW(wcs, 2, 1, 0)
               + (X(f, 0, 1) - cc) * LW(wcs, 3, 1, 0);
            c3 = (X(f, 1, 0) - cc) * LW(wcs, 4, 1, 0);
        } else if (i <= HSc - 1) {
            // ---- E: row 0, cols 1..HS-1 ----
            const int m = i - 1;
            c0 = (X(fp, HSc - 1, HSc + m) - cc) * LW(we, 0, 511, m);
            c1 = (X(f, 1, i + 1) - cc) * LW(we, 1, 511, m);
            c2 = (X(fp, HSc - 1, HSc + 1 + m) - cc) * LW(we, 2, 511, m)
               + (X(f, 0, i + 1) - cc) * LW(we, 3, 511, m);
            c3 = (X(f, 0, i - 1) - cc) * LW(we, 4, 511, m)
               + (X(f, 1, i)     - cc) * LW(we, 5, 511, m);
        } else if (i == HSc) {
            // ---- CN ----
            c0 = (X(fp, HSc - 1, Sc - 1) - cc) * LW(wcn, 0, 1, 0);
            c1 = (X(f, 1, HSc + 1) - cc) * LW(wcn, 1, 1, 0);
            c2 = (X(f, 0, HSc + 1) - cc) * LW(wcn, 2, 1, 0);
            c3 = (X(f, 0, HSc - 1) - cc) * LW(wcn, 3, 1, 0)
               + (X(f, 1, HSc)     - cc) * LW(wcn, 4, 1, 0);
        } else if (i < Sc - 1) {
            // ---- NE: row 0, cols HS+1..S-2 ----
            const int m = i - (HSc + 1);
            c0 = (X(fp, 510 - m, Sc - 1) - cc) * LW(wne, 0, 510, m)
               + (X(fp, 511 - m, Sc - 1) - cc) * LW(wne, 1, 510, m);
            c1 = (X(f, 1, i + 1) - cc) * LW(wne, 2, 510, m)
               + (X(f, 1, i)     - cc) * LW(wne, 3, 510, m);
            c2 = (X(f, 0, i + 1) - cc) * LW(wne, 4, 510, m);
            c3 = (X(f, 0, i - 1) - cc) * LW(wne, 5, 510, m);
        } else {
            // ---- NNE: row 0, col S-1 ----
            const float p1 = poles[b * 2 + 1];
            c0 = (X(fp, 0, Sc - 1) - cc) * LW(wnne, 0, 1, 0)
               + (X(fp, 1, Sc - 1) - cc) * LW(wnne, 1, 1, 0);
            c1 = (X(fn, 0, Sc - 1) - cc) * LW(wnne, 2, 1, 0)
               + (X(f,  1, Sc - 1) - cc) * LW(wnne, 3, 1, 0);
            c2 = (p1 - cc) * LW(wnne, 4, 1, 0);
            c3 = (X(f, 0, Sc - 2) - cc) * LW(wnne, 5, 1, 0);
        }
    } else { // j == HSc-1
        if (i == 0) {
            // ---- SSE ----
            const float p0 = poles[b * 2 + 0];
            c0 = (X(fp, HSc - 1, 0) - cc) * LW(wsse, 0, 1, 0);
            c1 = (X(fn, HSc - 1, 0) - cc) * LW(wsse, 1, 1, 0);
            c2 = (X(f, HSc - 2, 0) - cc) * LW(wsse, 2, 1, 0)
               + (X(f, HSc - 1, 1) - cc) * LW(wsse, 3, 1, 0);
            c3 = (p0 - cc) * LW(wsse, 4, 1, 0);
        } else if (i <= HSc - 1) {
            // ---- SW: row HS-1, cols 1..HS-1 ----
            const int m = i - 1;
            c0 = (X(f, HSc - 2, i - 1) - cc) * LW(wsw, 0, 511, m);
            c1 = (X(fn, 510 - m, 0) - cc) * LW(wsw, 1, 511, m);
            c2 = (X(f, HSc - 2, i)     - cc) * LW(wsw, 2, 511, m)
               + (X(f, HSc - 1, i + 1) - cc) * LW(wsw, 3, 511, m);
            c3 = (X(f, HSc - 1, i - 1) - cc) * LW(wsw, 4, 511, m)
               + (X(fn, 511 - m, 0)    - cc) * LW(wsw, 5, 511, m);
        } else if (i < Sc - 1) {
            // ---- WE (w_west): row HS-1, cols HS..S-2 ----
            const int m = i - HSc;
            c0 = (X(f, HSc - 2, i - 1) - cc) * LW(wwe, 0, 511, m);
            c1 = (X(fn, 0, 1 + m) - cc) * LW(wwe, 1, 511, m);
            c2 = (X(f, HSc - 2, i)     - cc) * LW(wwe, 2, 511, m)
               + (X(f, HSc - 1, i + 1) - cc) * LW(wwe, 3, 511, m);
            c3 = (X(f, HSc - 1, i - 1) - cc) * LW(wwe, 4, 511, m)
               + (X(fn, 0, m)          - cc) * LW(wwe, 5, 511, m);
        } else {
            // ---- NWW: row HS-1, col S-1 ----
            c0 = (X(f, HSc - 2, Sc - 2) - cc) * LW(wnww, 0, 1, 0);
            c1 = (X(fn, 0, HSc) - cc) * LW(wnww, 1, 1, 0);
            c2 = (X(f, HSc - 2, Sc - 1) - cc) * LW(wnww, 2, 1, 0)
               + (X(fn, 0, HSc + 1)     - cc) * LW(wnww, 3, 1, 0);
            c3 = (X(f, HSc - 1, Sc - 2) - cc) * LW(wnww, 4, 1, 0)
               + (X(fn, 0, HSc - 1)     - cc) * LW(wnww, 5, 1, 0);
        }
    }

    const size_t cs = (size_t)NFc * HSc * Sc;                  // component-plane stride
    const size_t ob = ((size_t)b * 4 * NFc + f) * (HSc * Sc)
                    + (size_t)j * Sc + (size_t)i;
    out[ob]          = c0;
    out[ob + cs]     = c1;
    out[ob + 2 * cs] = c2;
    out[ob + 3 * cs] = c3;
}

extern "C" void kernel_launch(void* const* d_in, const int* in_sizes, int n_in,
                              void* d_out, int out_size, void* d_ws, size_t ws_size,
                              hipStream_t stream) {
    const float* x    = (const float*)d_in[0];
    const float* pl   = (const float*)d_in[1];
    const float* wi   = (const float*)d_in[2];
    const float* we   = (const float*)d_in[3];
    const float* wcn  = (const float*)d_in[4];
    const float* wne  = (const float*)d_in[5];
    const float* wnne = (const float*)d_in[6];
    const float* wnw  = (const float*)d_in[7];
    const float* wnww = (const float*)d_in[8];
    const float* wwe  = (const float*)d_in[9];
    const float* wsw  = (const float*)d_in[10];
    const float* wsse = (const float*)d_in[11];
    const float* wse  = (const float*)d_in[12];
    const float* wcs  = (const float*)d_in[13];
    float* out = (float*)d_out;

    dim3 block(256, 1, 1);
    dim3 grid(Sc / 256, HSc, Bc * NFc);
    icograd_kernel<<<grid, block, 0, stream>>>(x, pl, wi, we, wcn, wne, wnne, wnw,
                                               wnww, wwe, wsw, wsse, wse, wcs, out);
}

// Round 4
// 262.011 us; speedup vs baseline: 1.0001x; 1.0001x over previous
//
#include <hip/hip_runtime.h>

#define Bc  4
#define NFc 5
#define HSc 512
#define Sc  1024
#define WSr (Sc - 2)            // 1022, w_inner row length
#define WSp ((HSc - 2) * WSr)   // w_inner plane stride

typedef float f4 __attribute__((ext_vector_type(4)));

// unaligned (4B-aligned) 16-byte load
static __device__ __forceinline__ f4 load4u(const float* p) {
    f4 r;
    __builtin_memcpy(&r, p, 16);
    return r;
}

// scalar inner-stencil for one (j,i), 1<=j<=510, 1<=i<=1022
static __device__ __forceinline__ void inner_scalar(
    const float* __restrict__ xf, const float* __restrict__ wi,
    int j, int i, float cc, float* c)
{
    const size_t wb = (size_t)(j - 1) * WSr + (i - 1);
    const float w0 = wi[wb];
    const float w1 = wi[wb + WSp];
    const float w2 = wi[wb + 2 * (size_t)WSp];
    const float w3 = wi[wb + 3 * (size_t)WSp];
    const float w4 = wi[wb + 4 * (size_t)WSp];
    const float w5 = wi[wb + 5 * (size_t)WSp];
    c[0] = (xf[(size_t)(j - 1) * Sc + (i - 1)] - cc) * w0;
    c[1] = (xf[(size_t)(j + 1) * Sc + (i + 1)] - cc) * w1;
    c[2] = (xf[(size_t)(j - 1) * Sc + i] - cc) * w2
         + (xf[(size_t)j * Sc + (i + 1)] - cc) * w3;
    c[3] = (xf[(size_t)j * Sc + (i - 1)] - cc) * w4
         + (xf[(size_t)(j + 1) * Sc + i] - cc) * w5;
}

// ---------------- bulk kernel: rows 1..510, all 1024 cols ----------------
__global__ __launch_bounds__(256) void icograd_bulk(
    const float* __restrict__ x, const float* __restrict__ wi,
    const float* __restrict__ wnw, const float* __restrict__ wse,
    float* __restrict__ out)
{
    const int t  = threadIdx.x;
    const int j  = blockIdx.x + 1;        // 1..510
    const int bf = blockIdx.y;
    const int b  = bf / NFc;
    const int f  = bf % NFc;

    const size_t xb = (size_t)b * (NFc * HSc * Sc);
    const float* xf = x + xb + (size_t)f * (HSc * Sc);
    const float* rm = xf + (size_t)(j - 1) * Sc;
    const float* rc = xf + (size_t)j * Sc;
    const float* rp = xf + (size_t)(j + 1) * Sc;
    const int i0 = t * 4;

    float c0[4], c1[4], c2[4], c3[4];

    if (t >= 1 && t <= 254) {
        // -------- vector path: cols i0..i0+3, all inner --------
        const f4 xm = *(const f4*)(rm + i0);
        const f4 xc = *(const f4*)(rc + i0);
        const f4 xp = *(const f4*)(rp + i0);
        const float xml = rm[i0 - 1];
        const float xcl = rc[i0 - 1];
        const float xcr = rc[i0 + 4];
        const float xpr = rp[i0 + 4];

        const float* wrow = wi + (size_t)(j - 1) * WSr + (i0 - 1);
        const f4 w0 = load4u(wrow);
        const f4 w1 = load4u(wrow + (size_t)WSp);
        const f4 w2 = load4u(wrow + 2 * (size_t)WSp);
        const f4 w3 = load4u(wrow + 3 * (size_t)WSp);
        const f4 w4 = load4u(wrow + 4 * (size_t)WSp);
        const f4 w5 = load4u(wrow + 5 * (size_t)WSp);

        const float am1[4] = {xml, xm.x, xm.y, xm.z};   // X(j-1, i-1)
        const float acm[4] = {xcl, xc.x, xc.y, xc.z};   // X(j,   i-1)
        const float acp[4] = {xc.y, xc.z, xc.w, xcr};   // X(j,   i+1)
        const float app[4] = {xp.y, xp.z, xp.w, xpr};   // X(j+1, i+1)
        const float xcv[4] = {xc.x, xc.y, xc.z, xc.w};
        const float xmv[4] = {xm.x, xm.y, xm.z, xm.w};
        const float xpv[4] = {xp.x, xp.y, xp.z, xp.w};
        const float w0v[4] = {w0.x, w0.y, w0.z, w0.w};
        const float w1v[4] = {w1.x, w1.y, w1.z, w1.w};
        const float w2v[4] = {w2.x, w2.y, w2.z, w2.w};
        const float w3v[4] = {w3.x, w3.y, w3.z, w3.w};
        const float w4v[4] = {w4.x, w4.y, w4.z, w4.w};
        const float w5v[4] = {w5.x, w5.y, w5.z, w5.w};

#pragma unroll
        for (int e = 0; e < 4; ++e) {
            const float cc = xcv[e];
            c0[e] = (am1[e] - cc) * w0v[e];
            c1[e] = (app[e] - cc) * w1v[e];
            c2[e] = (xmv[e] - cc) * w2v[e] + (acp[e] - cc) * w3v[e];
            c3[e] = (acm[e] - cc) * w4v[e] + (xpv[e] - cc) * w5v[e];
        }
    } else if (t == 0) {
        // -------- cols 0..3: col 0 = SE boundary, cols 1..3 inner --------
        {   // SE, col 0
            const int m = j - 1;
            const int fp = (f == 0) ? 4 : f - 1;
            const float* xq = x + xb + (size_t)fp * (HSc * Sc);
            const float cc = rc[0];
            float cw[4];
            cw[0] = (xq[(size_t)(HSc - 1) * Sc + (511 - m)] - cc) * wse[0 * 510 + m]
                  + (xq[(size_t)(HSc - 1) * Sc + (510 - m)] - cc) * wse[1 * 510 + m];
            cw[1] = (rc[1] - cc) * wse[2 * 510 + m]
                  + (rp[1] - cc) * wse[3 * 510 + m];
            cw[2] = (rm[0] - cc) * wse[4 * 510 + m];
            cw[3] = (rp[0] - cc) * wse[5 * 510 + m];
            c0[0] = cw[0]; c1[0] = cw[1]; c2[0] = cw[2]; c3[0] = cw[3];
        }
#pragma unroll
        for (int e = 1; e < 4; ++e) {
            float cw[4];
            inner_scalar(xf, wi, j, e, rc[e], cw);
            c0[e] = cw[0]; c1[e] = cw[1]; c2[e] = cw[2]; c3[e] = cw[3];
        }
    } else {
        // t == 255: cols 1020..1022 inner, col 1023 = NW boundary
#pragma unroll
        for (int e = 0; e < 3; ++e) {
            const int i = 1020 + e;
            float cw[4];
            inner_scalar(xf, wi, j, i, rc[i], cw);
            c0[e] = cw[0]; c1[e] = cw[1]; c2[e] = cw[2]; c3[e] = cw[3];
        }
        {   // NW, col 1023
            const int m = j - 1;
            const int fn = (f == 4) ? 0 : f + 1;
            const float* xq = x + xb + (size_t)fn * (HSc * Sc);
            const float cc = rc[Sc - 1];
            float cw[4];
            cw[0] = (rm[Sc - 2] - cc) * wnw[0 * 510 + m];
            cw[1] = (xq[Sc - 2 - m] - cc) * wnw[1 * 510 + m];
            cw[2] = (rm[Sc - 1] - cc) * wnw[2 * 510 + m]
                  + (xq[Sc - 1 - m] - cc) * wnw[3 * 510 + m];
            cw[3] = (rc[Sc - 2] - cc) * wnw[4 * 510 + m]
                  + (rp[Sc - 1] - cc) * wnw[5 * 510 + m];
            c0[3] = cw[0]; c1[3] = cw[1]; c2[3] = cw[2]; c3[3] = cw[3];
        }
    }

    const size_t cs = (size_t)NFc * HSc * Sc;
    float* ob = out + ((size_t)b * (4 * NFc) + f) * (HSc * Sc)
                    + (size_t)j * Sc + i0;
    f4 o0 = {c0[0], c0[1], c0[2], c0[3]};
    f4 o1 = {c1[0], c1[1], c1[2], c1[3]};
    f4 o2 = {c2[0], c2[1], c2[2], c2[3]};
    f4 o3 = {c3[0], c3[1], c3[2], c3[3]};
    *(f4*)(ob)          = o0;
    *(f4*)(ob + cs)     = o1;
    *(f4*)(ob + 2 * cs) = o2;
    *(f4*)(ob + 3 * cs) = o3;
}

// ---------------- boundary kernel: rows j=0 and j=511, all cols ----------------
#define X(ff,jj,ii) x[xb + ((size_t)(ff)*HSc + (size_t)(jj))*Sc + (size_t)(ii)]
#define LW(arr,k,stride,m) (arr)[(k)*(stride)+(m)]

__global__ __launch_bounds__(256) void icograd_edge(
    const float* __restrict__ x,    const float* __restrict__ poles,
    const float* __restrict__ we,   const float* __restrict__ wcn,
    const float* __restrict__ wne,  const float* __restrict__ wnne,
    const float* __restrict__ wnww, const float* __restrict__ wwe,
    const float* __restrict__ wsw,  const float* __restrict__ wsse,
    const float* __restrict__ wcs,  float* __restrict__ out)
{
    const int i  = blockIdx.x * blockDim.x + threadIdx.x;
    const int j  = blockIdx.y ? (HSc - 1) : 0;
    const int bf = blockIdx.z;
    const int b  = bf / NFc;
    const int f  = bf % NFc;

    const size_t xb = (size_t)b * (NFc * HSc * Sc);
    const float  cc = X(f, j, i);
    const int fp = (f == 0) ? 4 : f - 1;
    const int fn = (f == 4) ? 0 : f + 1;

    float c0, c1, c2, c3;

    if (j == 0) {
        if (i == 0) {
            // ---- CS ----
            c0 = (X(fp, HSc - 1, HSc - 1) - cc) * wcs[0];
            c1 = (X(f, 1, 1) - cc) * wcs[1];
            c2 = (X(fp, HSc - 1, HSc) - cc) * wcs[2] + (X(f, 0, 1) - cc) * wcs[3];
            c3 = (X(f, 1, 0) - cc) * wcs[4];
        } else if (i <= HSc - 1) {
            // ---- E ----
            const int m = i - 1;
            c0 = (X(fp, HSc - 1, HSc + m) - cc) * LW(we, 0, 511, m);
            c1 = (X(f, 1, i + 1) - cc) * LW(we, 1, 511, m);
            c2 = (X(fp, HSc - 1, HSc + 1 + m) - cc) * LW(we, 2, 511, m)
               + (X(f, 0, i + 1) - cc) * LW(we, 3, 511, m);
            c3 = (X(f, 0, i - 1) - cc) * LW(we, 4, 511, m)
               + (X(f, 1, i)     - cc) * LW(we, 5, 511, m);
        } else if (i == HSc) {
            // ---- CN ----
            c0 = (X(fp, HSc - 1, Sc - 1) - cc) * wcn[0];
            c1 = (X(f, 1, HSc + 1) - cc) * wcn[1];
            c2 = (X(f, 0, HSc + 1) - cc) * wcn[2];
            c3 = (X(f, 0, HSc - 1) - cc) * wcn[3] + (X(f, 1, HSc) - cc) * wcn[4];
        } else if (i < Sc - 1) {
            // ---- NE ----
            const int m = i - (HSc + 1);
            c0 = (X(fp, 510 - m, Sc - 1) - cc) * LW(wne, 0, 510, m)
               + (X(fp, 511 - m, Sc - 1) - cc) * LW(wne, 1, 510, m);
            c1 = (X(f, 1, i + 1) - cc) * LW(wne, 2, 510, m)
               + (X(f, 1, i)     - cc) * LW(wne, 3, 510, m);
            c2 = (X(f, 0, i + 1) - cc) * LW(wne, 4, 510, m);
            c3 = (X(f, 0, i - 1) - cc) * LW(wne, 5, 510, m);
        } else {
            // ---- NNE ----
            const float p1 = poles[b * 2 + 1];
            c0 = (X(fp, 0, Sc - 1) - cc) * wnne[0]
               + (X(fp, 1, Sc - 1) - cc) * wnne[1];
            c1 = (X(fn, 0, Sc - 1) - cc) * wnne[2]
               + (X(f,  1, Sc - 1) - cc) * wnne[3];
            c2 = (p1 - cc) * wnne[4];
            c3 = (X(f, 0, Sc - 2) - cc) * wnne[5];
        }
    } else { // j == HSc-1
        if (i == 0) {
            // ---- SSE ----
            const float p0 = poles[b * 2 + 0];
            c0 = (X(fp, HSc - 1, 0) - cc) * wsse[0];
            c1 = (X(fn, HSc - 1, 0) - cc) * wsse[1];
            c2 = (X(f, HSc - 2, 0) - cc) * wsse[2]
               + (X(f, HSc - 1, 1) - cc) * wsse[3];
            c3 = (p0 - cc) * wsse[4];
        } else if (i <= HSc - 1) {
            // ---- SW ----
            const int m = i - 1;
            c0 = (X(f, HSc - 2, i - 1) - cc) * LW(wsw, 0, 511, m);
            c1 = (X(fn, 510 - m, 0) - cc) * LW(wsw, 1, 511, m);
            c2 = (X(f, HSc - 2, i)     - cc) * LW(wsw, 2, 511, m)
               + (X(f, HSc - 1, i + 1) - cc) * LW(wsw, 3, 511, m);
            c3 = (X(f, HSc - 1, i - 1) - cc) * LW(wsw, 4, 511, m)
               + (X(fn, 511 - m, 0)    - cc) * LW(wsw, 5, 511, m);
        } else if (i < Sc - 1) {
            // ---- WE ----
            const int m = i - HSc;
            c0 = (X(f, HSc - 2, i - 1) - cc) * LW(wwe, 0, 511, m);
            c1 = (X(fn, 0, 1 + m) - cc) * LW(wwe, 1, 511, m);
            c2 = (X(f, HSc - 2, i)     - cc) * LW(wwe, 2, 511, m)
               + (X(f, HSc - 1, i + 1) - cc) * LW(wwe, 3, 511, m);
            c3 = (X(f, HSc - 1, i - 1) - cc) * LW(wwe, 4, 511, m)
               + (X(fn, 0, m)          - cc) * LW(wwe, 5, 511, m);
        } else {
            // ---- NWW ----
            c0 = (X(f, HSc - 2, Sc - 2) - cc) * wnww[0];
            c1 = (X(fn, 0, HSc) - cc) * wnww[1];
            c2 = (X(f, HSc - 2, Sc - 1) - cc) * wnww[2]
               + (X(fn, 0, HSc + 1)     - cc) * wnww[3];
            c3 = (X(f, HSc - 1, Sc - 2) - cc) * wnww[4]
               + (X(fn, 0, HSc - 1)     - cc) * wnww[5];
        }
    }

    const size_t cs = (size_t)NFc * HSc * Sc;
    const size_t ob = ((size_t)b * (4 * NFc) + f) * (HSc * Sc)
                    + (size_t)j * Sc + (size_t)i;
    out[ob]          = c0;
    out[ob + cs]     = c1;
    out[ob + 2 * cs] = c2;
    out[ob + 3 * cs] = c3;
}

extern "C" void kernel_launch(void* const* d_in, const int* in_sizes, int n_in,
                              void* d_out, int out_size, void* d_ws, size_t ws_size,
                              hipStream_t stream) {
    const float* x    = (const float*)d_in[0];
    const float* pl   = (const float*)d_in[1];
    const float* wi   = (const float*)d_in[2];
    const float* we   = (const float*)d_in[3];
    const float* wcn  = (const float*)d_in[4];
    const float* wne  = (const float*)d_in[5];
    const float* wnne = (const float*)d_in[6];
    const float* wnw  = (const float*)d_in[7];
    const float* wnww = (const float*)d_in[8];
    const float* wwe  = (const float*)d_in[9];
    const float* wsw  = (const float*)d_in[10];
    const float* wsse = (const float*)d_in[11];
    const float* wse  = (const float*)d_in[12];
    const float* wcs  = (const float*)d_in[13];
    float* out = (float*)d_out;

    // bulk: rows 1..510, one block per row per (b,f)
    icograd_bulk<<<dim3(HSc - 2, Bc * NFc, 1), dim3(256, 1, 1), 0, stream>>>(
        x, wi, wnw, wse, out);
    // edges: rows 0 and 511
    icograd_edge<<<dim3(Sc / 256, 2, Bc * NFc), dim3(256, 1, 1), 0, stream>>>(
        x, pl, we, wcn, wne, wnne, wnww, wwe, wsw, wsse, wcs, out);
}